// Round 10
// baseline (5213.138 us; speedup 1.0000x reference)
//
#include <hip/hip_runtime.h>
#include <hip/hip_bf16.h>
#include <hip/hip_cooperative_groups.h>

namespace cg = cooperative_groups;

#define K_HOPS 10
#define D_IN   128
#define D_OUT  32

// ---------------------------------------------------------------------------
// Kernel 0: detect edge dtype (int64 vs int32) + compute Taylor coefficients
// ---------------------------------------------------------------------------
__global__ void detect_coeffs_kernel(const void* __restrict__ edges,
                                     const float* __restrict__ t_ptr,
                                     float* __restrict__ coeffs,
                                     int* __restrict__ flag64) {
    if (blockIdx.x == 0 && threadIdx.x == 0) {
        const int* e32 = (const int*)edges;
        int is64 = 1;
        for (int i = 1; i < 128; i += 2) {
            if (e32[i] != 0) { is64 = 0; break; }
        }
        *flag64 = is64;
        float t = *t_ptr;
        float c = expf(-t);
        coeffs[0] = c;
        for (int k = 1; k <= K_HOPS; ++k) {
            c = c * t / (float)k;
            coeffs[k] = c;
        }
    }
}

__device__ __forceinline__ int ld_idx(const void* p, long long i, int is64) {
    return is64 ? (int)((const long long*)p)[i] : ((const int*)p)[i];
}

// ---------------------------------------------------------------------------
// Kernel 1: in-degree count (dst side, self-loop added later as +1)
// ---------------------------------------------------------------------------
__global__ void degree_kernel(const void* __restrict__ edges, long long E,
                              int* __restrict__ degcnt,
                              const int* __restrict__ flag64) {
    int is64 = *flag64;
    long long i = (long long)blockIdx.x * blockDim.x + threadIdx.x;
    if (i < E) {
        int d = ld_idx(edges, E + i, is64);
        atomicAdd(&degcnt[d], 1);
    }
}

// ---------------------------------------------------------------------------
// Kernel 2: dinv = rsqrt(deg + 1)
// ---------------------------------------------------------------------------
__global__ void dinv_kernel(const int* __restrict__ degcnt,
                            float* __restrict__ dinv, int N) {
    int i = blockIdx.x * blockDim.x + threadIdx.x;
    if (i < N) {
        dinv[i] = rsqrtf((float)(degcnt[i] + 1));
    }
}

// ---------------------------------------------------------------------------
// Hierarchical exclusive scan: 1024 elems / 256-thread block, int4 coalesced.
// ---------------------------------------------------------------------------
__global__ void __launch_bounds__(256)
scan_sums_kernel(const int* __restrict__ degcnt, int* __restrict__ blocksums,
                 int N) {
    __shared__ int red[256];
    int tid = threadIdx.x;
    int i0 = blockIdx.x * 1024 + tid * 4;
    int s = 0;
    if (i0 + 3 < N) {
        int4 v = *(const int4*)(degcnt + i0);
        s = v.x + v.y + v.z + v.w;
    } else {
#pragma unroll
        for (int j = 0; j < 4; ++j) {
            int i = i0 + j;
            if (i < N) s += degcnt[i];
        }
    }
    red[tid] = s;
    __syncthreads();
    for (int off = 128; off > 0; off >>= 1) {
        if (tid < off) red[tid] += red[tid + off];
        __syncthreads();
    }
    if (tid == 0) blocksums[blockIdx.x] = red[0];
}

__global__ void __launch_bounds__(1024)
scan_offsets_kernel(const int* __restrict__ blocksums,
                    int* __restrict__ blockoffs, int* __restrict__ row_ptr,
                    int nblocks, int N) {
    __shared__ int sh[1024];
    int tid = threadIdx.x;
    sh[tid] = (tid < nblocks) ? blocksums[tid] : 0;
    __syncthreads();
    for (int off = 1; off < 1024; off <<= 1) {
        int u = (tid >= off) ? sh[tid - off] : 0;
        __syncthreads();
        sh[tid] += u;
        __syncthreads();
    }
    if (tid < nblocks) blockoffs[tid] = (tid == 0) ? 0 : sh[tid - 1];
    if (tid == 0) row_ptr[N] = sh[nblocks - 1];
}

__global__ void __launch_bounds__(256)
scan_write_kernel(const int* __restrict__ degcnt,
                  const int* __restrict__ blockoffs,
                  int* __restrict__ row_ptr, int N) {
    __shared__ int red[256];
    int tid = threadIdx.x;
    int i0 = blockIdx.x * 1024 + tid * 4;
    int a0 = 0, a1 = 0, a2 = 0, a3 = 0;
    if (i0 + 3 < N) {
        int4 v = *(const int4*)(degcnt + i0);
        a0 = v.x; a1 = v.y; a2 = v.z; a3 = v.w;
    } else {
        if (i0     < N) a0 = degcnt[i0];
        if (i0 + 1 < N) a1 = degcnt[i0 + 1];
        if (i0 + 2 < N) a2 = degcnt[i0 + 2];
        if (i0 + 3 < N) a3 = degcnt[i0 + 3];
    }
    red[tid] = a0 + a1 + a2 + a3;
    __syncthreads();
    for (int off = 1; off < 256; off <<= 1) {
        int u = (tid >= off) ? red[tid - off] : 0;
        __syncthreads();
        red[tid] += u;
        __syncthreads();
    }
    int pre = blockoffs[blockIdx.x] + ((tid == 0) ? 0 : red[tid - 1]);
    int p0 = pre, p1 = p0 + a0, p2 = p1 + a1, p3 = p2 + a2;
    if (i0 + 3 < N) {
        *(int4*)(row_ptr + i0) = make_int4(p0, p1, p2, p3);
    } else {
        if (i0     < N) row_ptr[i0]     = p0;
        if (i0 + 1 < N) row_ptr[i0 + 1] = p1;
        if (i0 + 2 < N) row_ptr[i0 + 2] = p2;
        if (i0 + 3 < N) row_ptr[i0 + 3] = p3;
    }
}

// ---------------------------------------------------------------------------
// Kernel 4: scatter edges into CSR (grouped by dst) — src index only (4B)
// ---------------------------------------------------------------------------
__global__ void scatter_kernel(const void* __restrict__ edges, long long E,
                               const int* __restrict__ row_ptr,
                               int* __restrict__ fill,
                               int* __restrict__ csr,
                               const int* __restrict__ flag64) {
    int is64 = *flag64;
    long long i = (long long)blockIdx.x * blockDim.x + threadIdx.x;
    if (i < E) {
        int s = ld_idx(edges, i, is64);
        int d = ld_idx(edges, E + i, is64);
        int pos = atomicAdd(&fill[d], 1);
        csr[row_ptr[d] + pos] = s;
    }
}

// ---------------------------------------------------------------------------
// Kernel 5: h = x @ W + b ; y0 = dinv*h ; out = coeffs[0] * y0
// ---------------------------------------------------------------------------
#define NB 64
__global__ void __launch_bounds__(256)
proj_kernel(const float* __restrict__ x, const float* __restrict__ W,
            const float* __restrict__ b, const float* __restrict__ coeffs,
            const float* __restrict__ dinv,
            float* __restrict__ y0, float* __restrict__ out, int N) {
    __shared__ float Wl[D_IN * D_OUT];
    __shared__ float bl[D_OUT];
    __shared__ float xl[NB * (D_IN + 1)];

    int tid = threadIdx.x;
    for (int i = tid; i < D_IN * D_OUT; i += 256) Wl[i] = W[i];
    if (tid < D_OUT) bl[tid] = b[tid];

    int n0 = blockIdx.x * NB;
    for (int v = tid; v < NB * D_IN / 4; v += 256) {
        int flat = v * 4;
        long long gflat = (long long)n0 * D_IN + flat;
        float4 val = make_float4(0.f, 0.f, 0.f, 0.f);
        if (gflat + 3 < (long long)N * D_IN) {
            val = *(const float4*)(x + gflat);
        }
        int node = flat >> 7;
        int j    = flat & 127;
        float* p = &xl[node * (D_IN + 1) + j];
        p[0] = val.x; p[1] = val.y; p[2] = val.z; p[3] = val.w;
    }
    __syncthreads();

    int node_l = tid >> 2;
    int gnode  = n0 + node_l;
    int f0     = (tid & 3) * 8;
    float acc[8];
#pragma unroll
    for (int ff = 0; ff < 8; ++ff) acc[ff] = 0.f;

    if (gnode < N) {
        const float* xr = &xl[node_l * (D_IN + 1)];
        for (int j = 0; j < D_IN; ++j) {
            float xv = xr[j];
#pragma unroll
            for (int ff = 0; ff < 8; ++ff) {
                acc[ff] += xv * Wl[j * D_OUT + f0 + ff];
            }
        }
        float c0 = coeffs[0];
        float dv = dinv[gnode];
        size_t base = (size_t)gnode * D_OUT + f0;
#pragma unroll
        for (int ff = 0; ff < 8; ++ff) {
            float yv = dv * (acc[ff] + bl[f0 + ff]);
            y0[base + ff]  = yv;
            out[base + ff] = c0 * yv;
        }
    }
}

// ---------------------------------------------------------------------------
// Device helper: one hop body for one (node, g) slot.
// ---------------------------------------------------------------------------
__device__ __forceinline__ void hop_body(
    const float4* __restrict__ curv, float4* __restrict__ nxtv,
    float4* __restrict__ outv,
    const int* __restrict__ csr, const int* __restrict__ row_ptr,
    const float* __restrict__ dinv, const int* __restrict__ degcnt,
    float c, bool last, int node, int g) {
    int start = row_ptr[node];
    int len   = row_ptr[node + 1] - start;

    float ax = 0.f, ay = 0.f, az = 0.f, aw = 0.f;
    for (int base = 0; base < len; base += 8) {
        int rem = len - base;
        int cnt = rem < 8 ? rem : 8;
        int meta = csr[start + base + (g < cnt ? g : cnt - 1)];
#pragma unroll
        for (int j = 0; j < 8; ++j) {
            if (j < cnt) {   // uniform within the 8-lane group: clean exec mask
                int s = __shfl(meta, j, 8);
                float4 v = curv[(s << 3) + g];
                ax += v.x; ay += v.y; az += v.z; aw += v.w;
            }
        }
    }
    // self loop
    float4 sv = curv[(node << 3) + g];
    ax += sv.x; ay += sv.y; az += sv.z; aw += sv.w;

    float dv = dinv[node];
    float s2 = dv * dv;
    float4 y = make_float4(ax * s2, ay * s2, az * s2, aw * s2);

    int o = (node << 3) + g;
    nxtv[o] = y;
    float4 ov = outv[o];
    ov.x += c * y.x; ov.y += c * y.y; ov.z += c * y.z; ov.w += c * y.w;
    if (last) {
        float sc = sqrtf((float)(degcnt[node] + 1));
        ov.x *= sc; ov.y *= sc; ov.z *= sc; ov.w *= sc;
    }
    outv[o] = ov;
}

// ---------------------------------------------------------------------------
// Kernel 6a: ALL hops in one cooperative persistent kernel (grid.sync between
// hops; final sqrt(deg+1) scale folded into the last hop's out write).
// ---------------------------------------------------------------------------
__global__ void __launch_bounds__(256)
hops_kernel(float* __restrict__ buf0, float* __restrict__ buf1,
            float* __restrict__ out,
            const int* __restrict__ csr, const int* __restrict__ row_ptr,
            const float* __restrict__ dinv, const float* __restrict__ coeffs,
            const int* __restrict__ degcnt, int N) {
    cg::grid_group grid = cg::this_grid();
    int tid0 = blockIdx.x * blockDim.x + threadIdx.x;
    int nthr = gridDim.x * blockDim.x;
    int total = N * 8;

    float* cur = buf0;
    float* nxt = buf1;
    for (int k = 1; k <= K_HOPS; ++k) {
        float c = coeffs[k];
        bool last = (k == K_HOPS);
        const float4* curv = (const float4*)cur;
        float4* nxtv = (float4*)nxt;
        float4* outv = (float4*)out;
        for (int gtid = tid0; gtid < total; gtid += nthr) {
            hop_body(curv, nxtv, outv, csr, row_ptr, dinv, degcnt, c, last,
                     gtid >> 3, gtid & 7);
        }
        float* tmp = cur; cur = nxt; nxt = tmp;
        if (!last) {
            __threadfence();   // device-scope: make nxt visible across XCDs
            grid.sync();
        }
    }
}

// ---------------------------------------------------------------------------
// Kernel 6b: single-hop fallback (if cooperative launch is unavailable)
// ---------------------------------------------------------------------------
__global__ void __launch_bounds__(256)
hop_kernel(const float* __restrict__ cur, float* __restrict__ nxt,
           float* __restrict__ out,
           const int* __restrict__ csr, const int* __restrict__ row_ptr,
           const float* __restrict__ dinv, const float* __restrict__ coeffs,
           const int* __restrict__ degcnt, int k, int N) {
    int gtid = blockIdx.x * blockDim.x + threadIdx.x;
    if (gtid >= N * 8) return;
    hop_body((const float4*)cur, (float4*)nxt, (float4*)out, csr, row_ptr,
             dinv, degcnt, coeffs[k], k == K_HOPS, gtid >> 3, gtid & 7);
}

// ---------------------------------------------------------------------------
// launch
// ---------------------------------------------------------------------------
extern "C" void kernel_launch(void* const* d_in, const int* in_sizes, int n_in,
                              void* d_out, int out_size, void* d_ws, size_t ws_size,
                              hipStream_t stream) {
    const float* x     = (const float*)d_in[0];
    const void*  edges = d_in[1];
    const float* W     = (const float*)d_in[2];
    const float* b     = (const float*)d_in[3];
    const float* t     = (const float*)d_in[4];
    float*       out   = (float*)d_out;

    long long E = in_sizes[1] / 2;
    int       N = in_sizes[0] / D_IN;
    int nblocks = (N + 1023) / 1024;

    char*  ws  = (char*)d_ws;
    size_t off = 0;
    auto alloc = [&](size_t bytes) -> void* {
        void* p = ws + off;
        off = (off + bytes + 255) & ~(size_t)255;
        return p;
    };
    float* coeffs    = (float*)alloc(64);
    int*   flag64    = (int*)alloc(4);
    int*   degcnt    = (int*)alloc((size_t)N * 8);   // degcnt + fill
    int*   fill      = degcnt + N;
    float* dinv      = (float*)alloc((size_t)N * 4);
    int*   row_ptr   = (int*)alloc(((size_t)N + 1) * 4);
    int*   blocksums = (int*)alloc((size_t)nblocks * 4);
    int*   blockoffs = (int*)alloc((size_t)nblocks * 4);
    int*   csr       = (int*)alloc((size_t)E * 4);
    float* buf0      = (float*)alloc((size_t)N * D_OUT * 4);
    float* buf1      = (float*)alloc((size_t)N * D_OUT * 4);
    (void)ws_size;

    detect_coeffs_kernel<<<1, 64, 0, stream>>>(edges, t, coeffs, flag64);
    hipMemsetAsync(degcnt, 0, (size_t)N * 8, stream);

    int egrid = (int)((E + 255) / 256);
    degree_kernel<<<egrid, 256, 0, stream>>>(edges, E, degcnt, flag64);
    dinv_kernel<<<(N + 255) / 256, 256, 0, stream>>>(degcnt, dinv, N);

    scan_sums_kernel<<<nblocks, 256, 0, stream>>>(degcnt, blocksums, N);
    scan_offsets_kernel<<<1, 1024, 0, stream>>>(blocksums, blockoffs, row_ptr,
                                                nblocks, N);
    scan_write_kernel<<<nblocks, 256, 0, stream>>>(degcnt, blockoffs, row_ptr, N);

    scatter_kernel<<<egrid, 256, 0, stream>>>(edges, E, row_ptr, fill, csr,
                                              flag64);
    proj_kernel<<<(N + NB - 1) / NB, 256, 0, stream>>>(x, W, b, coeffs, dinv,
                                                       buf0, out, N);

    // ---- all 10 hops in one cooperative kernel ----
    int needed = (N * 8 + 255) / 256;
    int maxBlocksPerCU = 0;
    hipError_t qerr = hipOccupancyMaxActiveBlocksPerMultiprocessor(
        &maxBlocksPerCU, hops_kernel, 256, 0);
    int coopGrid = (qerr == hipSuccess && maxBlocksPerCU > 0)
                       ? maxBlocksPerCU * 256 : 1024;
    if (coopGrid > needed) coopGrid = needed;

    int Nv = N;
    void* args[] = {&buf0, &buf1, &out, &csr, &row_ptr,
                    &dinv, &coeffs, &degcnt, &Nv};
    hipError_t lerr = hipLaunchCooperativeKernel(
        reinterpret_cast<void*>(hops_kernel), dim3(coopGrid), dim3(256),
        args, 0, stream);

    if (lerr != hipSuccess) {
        // fallback: sequential per-hop launches (same math, final scale folded
        // into the k==K_HOPS hop)
        float* bufs[2] = {buf0, buf1};
        for (int k = 1; k <= K_HOPS; ++k) {
            hop_kernel<<<needed, 256, 0, stream>>>(
                bufs[(k - 1) & 1], bufs[k & 1], out, csr, row_ptr, dinv,
                coeffs, degcnt, k, N);
        }
    }
}

// Round 11
// 625.899 us; speedup vs baseline: 8.3290x; 8.3290x over previous
//
#include <hip/hip_runtime.h>
#include <hip/hip_bf16.h>

#define K_HOPS 10
#define D_IN   128
#define D_OUT  32

// ---------------------------------------------------------------------------
// Kernel 0: detect edge dtype (int64 vs int32) + compute Taylor coefficients
// ---------------------------------------------------------------------------
__global__ void detect_coeffs_kernel(const void* __restrict__ edges,
                                     const float* __restrict__ t_ptr,
                                     float* __restrict__ coeffs,
                                     int* __restrict__ flag64) {
    if (blockIdx.x == 0 && threadIdx.x == 0) {
        const int* e32 = (const int*)edges;
        int is64 = 1;
        for (int i = 1; i < 128; i += 2) {
            if (e32[i] != 0) { is64 = 0; break; }
        }
        *flag64 = is64;
        float t = *t_ptr;
        float c = expf(-t);
        coeffs[0] = c;
        for (int k = 1; k <= K_HOPS; ++k) {
            c = c * t / (float)k;
            coeffs[k] = c;
        }
    }
}

__device__ __forceinline__ int ld_idx(const void* p, long long i, int is64) {
    return is64 ? (int)((const long long*)p)[i] : ((const int*)p)[i];
}

// ---------------------------------------------------------------------------
// Kernel 1: in-degree count (dst side, self-loop added later as +1)
// ---------------------------------------------------------------------------
__global__ void degree_kernel(const void* __restrict__ edges, long long E,
                              int* __restrict__ degcnt,
                              const int* __restrict__ flag64) {
    int is64 = *flag64;
    long long i = (long long)blockIdx.x * blockDim.x + threadIdx.x;
    if (i < E) {
        int d = ld_idx(edges, E + i, is64);
        atomicAdd(&degcnt[d], 1);
    }
}

// ---------------------------------------------------------------------------
// Kernel 2: dinv = rsqrt(deg + 1)
// ---------------------------------------------------------------------------
__global__ void dinv_kernel(const int* __restrict__ degcnt,
                            float* __restrict__ dinv, int N) {
    int i = blockIdx.x * blockDim.x + threadIdx.x;
    if (i < N) {
        dinv[i] = rsqrtf((float)(degcnt[i] + 1));
    }
}

// ---------------------------------------------------------------------------
// Hierarchical exclusive scan: 1024 elems / 256-thread block, int4 coalesced.
// ---------------------------------------------------------------------------
__global__ void __launch_bounds__(256)
scan_sums_kernel(const int* __restrict__ degcnt, int* __restrict__ blocksums,
                 int N) {
    __shared__ int red[256];
    int tid = threadIdx.x;
    int i0 = blockIdx.x * 1024 + tid * 4;
    int s = 0;
    if (i0 + 3 < N) {
        int4 v = *(const int4*)(degcnt + i0);
        s = v.x + v.y + v.z + v.w;
    } else {
#pragma unroll
        for (int j = 0; j < 4; ++j) {
            int i = i0 + j;
            if (i < N) s += degcnt[i];
        }
    }
    red[tid] = s;
    __syncthreads();
    for (int off = 128; off > 0; off >>= 1) {
        if (tid < off) red[tid] += red[tid + off];
        __syncthreads();
    }
    if (tid == 0) blocksums[blockIdx.x] = red[0];
}

__global__ void __launch_bounds__(1024)
scan_offsets_kernel(const int* __restrict__ blocksums,
                    int* __restrict__ blockoffs, int* __restrict__ row_ptr,
                    int nblocks, int N) {
    __shared__ int sh[1024];
    int tid = threadIdx.x;
    sh[tid] = (tid < nblocks) ? blocksums[tid] : 0;
    __syncthreads();
    for (int off = 1; off < 1024; off <<= 1) {
        int u = (tid >= off) ? sh[tid - off] : 0;
        __syncthreads();
        sh[tid] += u;
        __syncthreads();
    }
    if (tid < nblocks) blockoffs[tid] = (tid == 0) ? 0 : sh[tid - 1];
    if (tid == 0) row_ptr[N] = sh[nblocks - 1];
}

__global__ void __launch_bounds__(256)
scan_write_kernel(const int* __restrict__ degcnt,
                  const int* __restrict__ blockoffs,
                  int* __restrict__ row_ptr, int N) {
    __shared__ int red[256];
    int tid = threadIdx.x;
    int i0 = blockIdx.x * 1024 + tid * 4;
    int a0 = 0, a1 = 0, a2 = 0, a3 = 0;
    if (i0 + 3 < N) {
        int4 v = *(const int4*)(degcnt + i0);
        a0 = v.x; a1 = v.y; a2 = v.z; a3 = v.w;
    } else {
        if (i0     < N) a0 = degcnt[i0];
        if (i0 + 1 < N) a1 = degcnt[i0 + 1];
        if (i0 + 2 < N) a2 = degcnt[i0 + 2];
        if (i0 + 3 < N) a3 = degcnt[i0 + 3];
    }
    red[tid] = a0 + a1 + a2 + a3;
    __syncthreads();
    for (int off = 1; off < 256; off <<= 1) {
        int u = (tid >= off) ? red[tid - off] : 0;
        __syncthreads();
        red[tid] += u;
        __syncthreads();
    }
    int pre = blockoffs[blockIdx.x] + ((tid == 0) ? 0 : red[tid - 1]);
    int p0 = pre, p1 = p0 + a0, p2 = p1 + a1, p3 = p2 + a2;
    if (i0 + 3 < N) {
        *(int4*)(row_ptr + i0) = make_int4(p0, p1, p2, p3);
    } else {
        if (i0     < N) row_ptr[i0]     = p0;
        if (i0 + 1 < N) row_ptr[i0 + 1] = p1;
        if (i0 + 2 < N) row_ptr[i0 + 2] = p2;
        if (i0 + 3 < N) row_ptr[i0 + 3] = p3;
    }
}

// ---------------------------------------------------------------------------
// Kernel 4: dst-partitioned scatter. 8 partition groups; group p handles only
// edges with (dst >> shift) == p, so each CSR cache line is written by blocks
// of a single group (ideally one XCD: part = blockIdx & 7 matches round-robin
// block->XCD). Kills the measured 16x write amplification (109MB for 6.4MB).
// ---------------------------------------------------------------------------
__global__ void __launch_bounds__(256)
scatter_kernel(const void* __restrict__ edges, long long E,
               const int* __restrict__ row_ptr,
               int* __restrict__ fill,
               int* __restrict__ csr,
               const int* __restrict__ flag64, int shift) {
    int is64 = *flag64;
    int part    = blockIdx.x & 7;
    int pbid    = blockIdx.x >> 3;
    int pblocks = gridDim.x >> 3;
    long long stride = (long long)pblocks * blockDim.x;
    for (long long i = (long long)pbid * blockDim.x + threadIdx.x; i < E;
         i += stride) {
        int d = ld_idx(edges, E + i, is64);
        if ((d >> shift) == part) {
            int s = ld_idx(edges, i, is64);
            int pos = atomicAdd(&fill[d], 1);
            csr[row_ptr[d] + pos] = s;
        }
    }
}

// ---------------------------------------------------------------------------
// Kernel 5: h = x @ W + b ; y0 = dinv*h ; out = coeffs[0] * y0
// ---------------------------------------------------------------------------
#define NB 64
__global__ void __launch_bounds__(256)
proj_kernel(const float* __restrict__ x, const float* __restrict__ W,
            const float* __restrict__ b, const float* __restrict__ coeffs,
            const float* __restrict__ dinv,
            float* __restrict__ y0, float* __restrict__ out, int N) {
    __shared__ float Wl[D_IN * D_OUT];
    __shared__ float bl[D_OUT];
    __shared__ float xl[NB * (D_IN + 1)];

    int tid = threadIdx.x;
    for (int i = tid; i < D_IN * D_OUT; i += 256) Wl[i] = W[i];
    if (tid < D_OUT) bl[tid] = b[tid];

    int n0 = blockIdx.x * NB;
    for (int v = tid; v < NB * D_IN / 4; v += 256) {
        int flat = v * 4;
        long long gflat = (long long)n0 * D_IN + flat;
        float4 val = make_float4(0.f, 0.f, 0.f, 0.f);
        if (gflat + 3 < (long long)N * D_IN) {
            val = *(const float4*)(x + gflat);
        }
        int node = flat >> 7;
        int j    = flat & 127;
        float* p = &xl[node * (D_IN + 1) + j];
        p[0] = val.x; p[1] = val.y; p[2] = val.z; p[3] = val.w;
    }
    __syncthreads();

    int node_l = tid >> 2;
    int gnode  = n0 + node_l;
    int f0     = (tid & 3) * 8;
    float acc[8];
#pragma unroll
    for (int ff = 0; ff < 8; ++ff) acc[ff] = 0.f;

    if (gnode < N) {
        const float* xr = &xl[node_l * (D_IN + 1)];
        for (int j = 0; j < D_IN; ++j) {
            float xv = xr[j];
#pragma unroll
            for (int ff = 0; ff < 8; ++ff) {
                acc[ff] += xv * Wl[j * D_OUT + f0 + ff];
            }
        }
        float c0 = coeffs[0];
        float dv = dinv[gnode];
        size_t base = (size_t)gnode * D_OUT + f0;
#pragma unroll
        for (int ff = 0; ff < 8; ++ff) {
            float yv = dv * (acc[ff] + bl[f0 + ff]);
            y0[base + ff]  = yv;
            out[base + ff] = c0 * yv;
        }
    }
}

// ---------------------------------------------------------------------------
// Kernel 6: one diffusion hop in y-space. 8 lanes/node, float4 gathers,
// unconditional clamped loads (round-8 structure: measured ~45us/hop).
//   y_k[v] = dinv[v]^2 * ( sum_{e:dst=v} y_{k-1}[src] + y_{k-1}[v] )
//   out[v] += coeffs[k] * y_k[v]   ( * sqrt(deg+1) folded into last hop )
// ---------------------------------------------------------------------------
__global__ void __launch_bounds__(256)
hop_kernel(const float* __restrict__ cur, float* __restrict__ nxt,
           float* __restrict__ out,
           const int* __restrict__ csr, const int* __restrict__ row_ptr,
           const float* __restrict__ dinv, const float* __restrict__ coeffs,
           const int* __restrict__ degcnt, int k, int N) {
    int gtid = blockIdx.x * blockDim.x + threadIdx.x;
    int node = gtid >> 3;      // 8 threads per node
    int g    = gtid & 7;       // float4 slot: features [4g, 4g+4)
    if (node >= N) return;

    int start = row_ptr[node];
    int len   = row_ptr[node + 1] - start;

    const float4* curv = (const float4*)cur;
    float ax = 0.f, ay = 0.f, az = 0.f, aw = 0.f;
    for (int base = 0; base < len; base += 8) {
        int rem = len - base;
        int cnt = rem < 8 ? rem : 8;
        // 8 lanes of the group batch-load up to 8 src indices (clamped tail)
        int meta = csr[start + base + (g < cnt ? g : cnt - 1)];
#pragma unroll
        for (int j = 0; j < 8; ++j) {
            int s = __shfl(meta, j, 8);        // broadcast within 8-lane group
            float4 v = curv[(s << 3) + g];     // clamped lanes repeat a valid row
            if (j < cnt) { ax += v.x; ay += v.y; az += v.z; aw += v.w; }
        }
    }
    // self loop
    float4 sv = curv[(node << 3) + g];
    ax += sv.x; ay += sv.y; az += sv.z; aw += sv.w;

    float dv = dinv[node];
    float s2 = dv * dv;
    float4 y = make_float4(ax * s2, ay * s2, az * s2, aw * s2);

    int o = (node << 3) + g;
    ((float4*)nxt)[o] = y;
    float c = coeffs[k];
    float4 ov = ((float4*)out)[o];
    ov.x += c * y.x; ov.y += c * y.y; ov.z += c * y.z; ov.w += c * y.w;
    if (k == K_HOPS) {   // fold final D^{1/2} rescale into the last hop
        float sc = sqrtf((float)(degcnt[node] + 1));
        ov.x *= sc; ov.y *= sc; ov.z *= sc; ov.w *= sc;
    }
    ((float4*)out)[o] = ov;
}

// ---------------------------------------------------------------------------
// launch
// ---------------------------------------------------------------------------
extern "C" void kernel_launch(void* const* d_in, const int* in_sizes, int n_in,
                              void* d_out, int out_size, void* d_ws, size_t ws_size,
                              hipStream_t stream) {
    const float* x     = (const float*)d_in[0];
    const void*  edges = d_in[1];
    const float* W     = (const float*)d_in[2];
    const float* b     = (const float*)d_in[3];
    const float* t     = (const float*)d_in[4];
    float*       out   = (float*)d_out;

    long long E = in_sizes[1] / 2;
    int       N = in_sizes[0] / D_IN;
    int nblocks = (N + 1023) / 1024;

    // partition shift: (N-1)>>shift must be <= 7 (8 partitions)
    int shift = 1;
    while ((((long long)N - 1) >> shift) > 7) shift++;

    char*  ws  = (char*)d_ws;
    size_t off = 0;
    auto alloc = [&](size_t bytes) -> void* {
        void* p = ws + off;
        off = (off + bytes + 255) & ~(size_t)255;
        return p;
    };
    float* coeffs    = (float*)alloc(64);
    int*   flag64    = (int*)alloc(4);
    int*   degcnt    = (int*)alloc((size_t)N * 8);   // degcnt + fill
    int*   fill      = degcnt + N;
    float* dinv      = (float*)alloc((size_t)N * 4);
    int*   row_ptr   = (int*)alloc(((size_t)N + 1) * 4);
    int*   blocksums = (int*)alloc((size_t)nblocks * 4);
    int*   blockoffs = (int*)alloc((size_t)nblocks * 4);
    int*   csr       = (int*)alloc((size_t)E * 4);
    float* buf0      = (float*)alloc((size_t)N * D_OUT * 4);
    float* buf1      = (float*)alloc((size_t)N * D_OUT * 4);
    (void)ws_size;

    detect_coeffs_kernel<<<1, 64, 0, stream>>>(edges, t, coeffs, flag64);
    hipMemsetAsync(degcnt, 0, (size_t)N * 8, stream);

    int egrid = (int)((E + 255) / 256);
    degree_kernel<<<egrid, 256, 0, stream>>>(edges, E, degcnt, flag64);
    dinv_kernel<<<(N + 255) / 256, 256, 0, stream>>>(degcnt, dinv, N);

    scan_sums_kernel<<<nblocks, 256, 0, stream>>>(degcnt, blocksums, N);
    scan_offsets_kernel<<<1, 1024, 0, stream>>>(blocksums, blockoffs, row_ptr,
                                                nblocks, N);
    scan_write_kernel<<<nblocks, 256, 0, stream>>>(degcnt, blockoffs, row_ptr, N);

    // dst-partitioned scatter: 8 groups x 768 blocks
    scatter_kernel<<<8 * 768, 256, 0, stream>>>(edges, E, row_ptr, fill, csr,
                                                flag64, shift);

    proj_kernel<<<(N + NB - 1) / NB, 256, 0, stream>>>(x, W, b, coeffs, dinv,
                                                       buf0, out, N);

    float* bufs[2] = {buf0, buf1};
    int hgrid = (int)(((long long)N * 8 + 255) / 256);
    for (int k = 1; k <= K_HOPS; ++k) {
        hop_kernel<<<hgrid, 256, 0, stream>>>(bufs[(k - 1) & 1], bufs[k & 1], out,
                                              csr, row_ptr, dinv, coeffs,
                                              degcnt, k, N);
    }
}

// Round 13
// 569.658 us; speedup vs baseline: 9.1514x; 1.0987x over previous
//
#include <hip/hip_runtime.h>
#include <hip/hip_bf16.h>
#include <hip/hip_fp16.h>

#define K_HOPS 10
#define D_IN   128
#define D_OUT  32

// ---------------------------------------------------------------------------
// f16x4 <-> f32x4 helpers (state is fp16; all accumulation stays f32)
// ---------------------------------------------------------------------------
__device__ __forceinline__ float4 h4_to_f4(uint2 u) {
    __half2* p = (__half2*)&u;
    float2 a = __half22float2(p[0]);
    float2 b = __half22float2(p[1]);
    return make_float4(a.x, a.y, b.x, b.y);
}
__device__ __forceinline__ uint2 f4_to_h4(float4 v) {
    uint2 u;
    __half2* p = (__half2*)&u;
    p[0] = __floats2half2_rn(v.x, v.y);
    p[1] = __floats2half2_rn(v.z, v.w);
    return u;
}

// ---------------------------------------------------------------------------
// Kernel 0: detect edge dtype (int64 vs int32) + compute Taylor coefficients
// ---------------------------------------------------------------------------
__global__ void detect_coeffs_kernel(const void* __restrict__ edges,
                                     const float* __restrict__ t_ptr,
                                     float* __restrict__ coeffs,
                                     int* __restrict__ flag64) {
    if (blockIdx.x == 0 && threadIdx.x == 0) {
        const int* e32 = (const int*)edges;
        int is64 = 1;
        for (int i = 1; i < 128; i += 2) {
            if (e32[i] != 0) { is64 = 0; break; }
        }
        *flag64 = is64;
        float t = *t_ptr;
        float c = expf(-t);
        coeffs[0] = c;
        for (int k = 1; k <= K_HOPS; ++k) {
            c = c * t / (float)k;
            coeffs[k] = c;
        }
    }
}

__device__ __forceinline__ int ld_idx(const void* p, long long i, int is64) {
    return is64 ? (int)((const long long*)p)[i] : ((const int*)p)[i];
}

// ---------------------------------------------------------------------------
// Kernel 1: in-degree count (dst side, self-loop added later as +1)
// ---------------------------------------------------------------------------
__global__ void degree_kernel(const void* __restrict__ edges, long long E,
                              int* __restrict__ degcnt,
                              const int* __restrict__ flag64) {
    int is64 = *flag64;
    long long i = (long long)blockIdx.x * blockDim.x + threadIdx.x;
    if (i < E) {
        int d = ld_idx(edges, E + i, is64);
        atomicAdd(&degcnt[d], 1);
    }
}

// ---------------------------------------------------------------------------
// Kernel 2: dinv = rsqrt(deg + 1)
// ---------------------------------------------------------------------------
__global__ void dinv_kernel(const int* __restrict__ degcnt,
                            float* __restrict__ dinv, int N) {
    int i = blockIdx.x * blockDim.x + threadIdx.x;
    if (i < N) {
        dinv[i] = rsqrtf((float)(degcnt[i] + 1));
    }
}

// ---------------------------------------------------------------------------
// Hierarchical exclusive scan: 1024 elems / 256-thread block, int4 coalesced.
// ---------------------------------------------------------------------------
__global__ void __launch_bounds__(256)
scan_sums_kernel(const int* __restrict__ degcnt, int* __restrict__ blocksums,
                 int N) {
    __shared__ int red[256];
    int tid = threadIdx.x;
    int i0 = blockIdx.x * 1024 + tid * 4;
    int s = 0;
    if (i0 + 3 < N) {
        int4 v = *(const int4*)(degcnt + i0);
        s = v.x + v.y + v.z + v.w;
    } else {
#pragma unroll
        for (int j = 0; j < 4; ++j) {
            int i = i0 + j;
            if (i < N) s += degcnt[i];
        }
    }
    red[tid] = s;
    __syncthreads();
    for (int off = 128; off > 0; off >>= 1) {
        if (tid < off) red[tid] += red[tid + off];
        __syncthreads();
    }
    if (tid == 0) blocksums[blockIdx.x] = red[0];
}

__global__ void __launch_bounds__(1024)
scan_offsets_kernel(const int* __restrict__ blocksums,
                    int* __restrict__ blockoffs, int* __restrict__ row_ptr,
                    int nblocks, int N) {
    __shared__ int sh[1024];
    int tid = threadIdx.x;
    sh[tid] = (tid < nblocks) ? blocksums[tid] : 0;
    __syncthreads();
    for (int off = 1; off < 1024; off <<= 1) {
        int u = (tid >= off) ? sh[tid - off] : 0;
        __syncthreads();
        sh[tid] += u;
        __syncthreads();
    }
    if (tid < nblocks) blockoffs[tid] = (tid == 0) ? 0 : sh[tid - 1];
    if (tid == 0) row_ptr[N] = sh[nblocks - 1];
}

__global__ void __launch_bounds__(256)
scan_write_kernel(const int* __restrict__ degcnt,
                  const int* __restrict__ blockoffs,
                  int* __restrict__ row_ptr, int N) {
    __shared__ int red[256];
    int tid = threadIdx.x;
    int i0 = blockIdx.x * 1024 + tid * 4;
    int a0 = 0, a1 = 0, a2 = 0, a3 = 0;
    if (i0 + 3 < N) {
        int4 v = *(const int4*)(degcnt + i0);
        a0 = v.x; a1 = v.y; a2 = v.z; a3 = v.w;
    } else {
        if (i0     < N) a0 = degcnt[i0];
        if (i0 + 1 < N) a1 = degcnt[i0 + 1];
        if (i0 + 2 < N) a2 = degcnt[i0 + 2];
        if (i0 + 3 < N) a3 = degcnt[i0 + 3];
    }
    red[tid] = a0 + a1 + a2 + a3;
    __syncthreads();
    for (int off = 1; off < 256; off <<= 1) {
        int u = (tid >= off) ? red[tid - off] : 0;
        __syncthreads();
        red[tid] += u;
        __syncthreads();
    }
    int pre = blockoffs[blockIdx.x] + ((tid == 0) ? 0 : red[tid - 1]);
    int p0 = pre, p1 = p0 + a0, p2 = p1 + a1, p3 = p2 + a2;
    if (i0 + 3 < N) {
        *(int4*)(row_ptr + i0) = make_int4(p0, p1, p2, p3);
    } else {
        if (i0     < N) row_ptr[i0]     = p0;
        if (i0 + 1 < N) row_ptr[i0 + 1] = p1;
        if (i0 + 2 < N) row_ptr[i0 + 2] = p2;
        if (i0 + 3 < N) row_ptr[i0 + 3] = p3;
    }
}

// ---------------------------------------------------------------------------
// Kernel 4: dst-partitioned scatter (round-11 structure, measured 74us,
// WRITE_SIZE 109->79MB). part = blockIdx&7 matches round-robin block->XCD.
// ---------------------------------------------------------------------------
__global__ void __launch_bounds__(256)
scatter_kernel(const void* __restrict__ edges, long long E,
               const int* __restrict__ row_ptr,
               int* __restrict__ fill,
               int* __restrict__ csr,
               const int* __restrict__ flag64, int shift) {
    int is64 = *flag64;
    int part    = blockIdx.x & 7;
    int pbid    = blockIdx.x >> 3;
    int pblocks = gridDim.x >> 3;
    long long stride = (long long)pblocks * blockDim.x;
    for (long long i = (long long)pbid * blockDim.x + threadIdx.x; i < E;
         i += stride) {
        int d = ld_idx(edges, E + i, is64);
        if ((d >> shift) == part) {
            int s = ld_idx(edges, i, is64);
            int pos = atomicAdd(&fill[d], 1);
            csr[row_ptr[d] + pos] = s;
        }
    }
}

// ---------------------------------------------------------------------------
// Kernel 5: h = x @ W + b ; y0 = f16(dinv*h) ; out = coeffs[0] * (dinv*h)
// ---------------------------------------------------------------------------
#define NB 64
__global__ void __launch_bounds__(256)
proj_kernel(const float* __restrict__ x, const float* __restrict__ W,
            const float* __restrict__ b, const float* __restrict__ coeffs,
            const float* __restrict__ dinv,
            __half* __restrict__ y0, float* __restrict__ out, int N) {
    __shared__ float Wl[D_IN * D_OUT];
    __shared__ float bl[D_OUT];
    __shared__ float xl[NB * (D_IN + 1)];

    int tid = threadIdx.x;
    for (int i = tid; i < D_IN * D_OUT; i += 256) Wl[i] = W[i];
    if (tid < D_OUT) bl[tid] = b[tid];

    int n0 = blockIdx.x * NB;
    for (int v = tid; v < NB * D_IN / 4; v += 256) {
        int flat = v * 4;
        long long gflat = (long long)n0 * D_IN + flat;
        float4 val = make_float4(0.f, 0.f, 0.f, 0.f);
        if (gflat + 3 < (long long)N * D_IN) {
            val = *(const float4*)(x + gflat);
        }
        int node = flat >> 7;
        int j    = flat & 127;
        float* p = &xl[node * (D_IN + 1) + j];
        p[0] = val.x; p[1] = val.y; p[2] = val.z; p[3] = val.w;
    }
    __syncthreads();

    int node_l = tid >> 2;
    int gnode  = n0 + node_l;
    int f0     = (tid & 3) * 8;
    float acc[8];
#pragma unroll
    for (int ff = 0; ff < 8; ++ff) acc[ff] = 0.f;

    if (gnode < N) {
        const float* xr = &xl[node_l * (D_IN + 1)];
        for (int j = 0; j < D_IN; ++j) {
            float xv = xr[j];
#pragma unroll
            for (int ff = 0; ff < 8; ++ff) {
                acc[ff] += xv * Wl[j * D_OUT + f0 + ff];
            }
        }
        float c0 = coeffs[0];
        float dv = dinv[gnode];
        size_t base = (size_t)gnode * D_OUT + f0;
        float yv[8];
#pragma unroll
        for (int ff = 0; ff < 8; ++ff) {
            yv[ff] = dv * (acc[ff] + bl[f0 + ff]);
            out[base + ff] = c0 * yv[ff];
        }
        // pack 8 f16 (16 B, aligned: base multiple of 8)
        uint2 u0 = f4_to_h4(make_float4(yv[0], yv[1], yv[2], yv[3]));
        uint2 u1 = f4_to_h4(make_float4(yv[4], yv[5], yv[6], yv[7]));
        uint4 packed = make_uint4(u0.x, u0.y, u1.x, u1.y);
        *(uint4*)(y0 + base) = packed;
    }
}

// ---------------------------------------------------------------------------
// Kernel 6: one diffusion hop in y-space. 8 lanes/node; f16 state rows are
// 64 B (1 cache line/edge = half the tx of f32) gathered as uint2 (4 halves)
// per lane; accumulation in f32; out stays f32.
//   y_k[v] = dinv[v]^2 * ( sum_{e:dst=v} y_{k-1}[src] + y_{k-1}[v] )
//   out[v] += coeffs[k] * y_k[v]   ( * sqrt(deg+1) folded into last hop )
// ---------------------------------------------------------------------------
__global__ void __launch_bounds__(256)
hop_kernel(const __half* __restrict__ cur, __half* __restrict__ nxt,
           float* __restrict__ out,
           const int* __restrict__ csr, const int* __restrict__ row_ptr,
           const float* __restrict__ dinv, const float* __restrict__ coeffs,
           const int* __restrict__ degcnt, int k, int N) {
    int gtid = blockIdx.x * blockDim.x + threadIdx.x;
    int node = gtid >> 3;      // 8 threads per node
    int g    = gtid & 7;       // slot: features [4g, 4g+4)
    if (node >= N) return;

    int start = row_ptr[node];
    int len   = row_ptr[node + 1] - start;

    const uint2* curv = (const uint2*)cur;   // row = 8 uint2 = 64 B
    float ax = 0.f, ay = 0.f, az = 0.f, aw = 0.f;
    for (int base = 0; base < len; base += 8) {
        int rem = len - base;
        int cnt = rem < 8 ? rem : 8;
        // 8 lanes of the group batch-load up to 8 src indices (clamped tail)
        int meta = csr[start + base + (g < cnt ? g : cnt - 1)];
#pragma unroll
        for (int j = 0; j < 8; ++j) {
            int s = __shfl(meta, j, 8);        // broadcast within 8-lane group
            float4 v = h4_to_f4(curv[(s << 3) + g]);  // clamped lanes repeat
            if (j < cnt) { ax += v.x; ay += v.y; az += v.z; aw += v.w; }
        }
    }
    // self loop
    float4 sv = h4_to_f4(curv[(node << 3) + g]);
    ax += sv.x; ay += sv.y; az += sv.z; aw += sv.w;

    float dv = dinv[node];
    float s2 = dv * dv;
    float4 y = make_float4(ax * s2, ay * s2, az * s2, aw * s2);

    int o = (node << 3) + g;
    ((uint2*)nxt)[o] = f4_to_h4(y);
    float c = coeffs[k];
    float4 ov = ((float4*)out)[o];
    ov.x += c * y.x; ov.y += c * y.y; ov.z += c * y.z; ov.w += c * y.w;
    if (k == K_HOPS) {   // fold final D^{1/2} rescale into the last hop
        float sc = sqrtf((float)(degcnt[node] + 1));
        ov.x *= sc; ov.y *= sc; ov.z *= sc; ov.w *= sc;
    }
    ((float4*)out)[o] = ov;
}

// ---------------------------------------------------------------------------
// launch
// ---------------------------------------------------------------------------
extern "C" void kernel_launch(void* const* d_in, const int* in_sizes, int n_in,
                              void* d_out, int out_size, void* d_ws, size_t ws_size,
                              hipStream_t stream) {
    const float* x     = (const float*)d_in[0];
    const void*  edges = d_in[1];
    const float* W     = (const float*)d_in[2];
    const float* b     = (const float*)d_in[3];
    const float* t     = (const float*)d_in[4];
    float*       out   = (float*)d_out;

    long long E = in_sizes[1] / 2;
    int       N = in_sizes[0] / D_IN;
    int nblocks = (N + 1023) / 1024;

    // partition shift: (N-1)>>shift must be <= 7 (8 partitions)
    int shift = 1;
    while ((((long long)N - 1) >> shift) > 7) shift++;

    char*  ws  = (char*)d_ws;
    size_t off = 0;
    auto alloc = [&](size_t bytes) -> void* {
        void* p = ws + off;
        off = (off + bytes + 255) & ~(size_t)255;
        return p;
    };
    float*  coeffs    = (float*)alloc(64);
    int*    flag64    = (int*)alloc(4);
    int*    degcnt    = (int*)alloc((size_t)N * 8);   // degcnt + fill
    int*    fill      = degcnt + N;
    float*  dinv      = (float*)alloc((size_t)N * 4);
    int*    row_ptr   = (int*)alloc(((size_t)N + 1) * 4);
    int*    blocksums = (int*)alloc((size_t)nblocks * 4);
    int*    blockoffs = (int*)alloc((size_t)nblocks * 4);
    int*    csr       = (int*)alloc((size_t)E * 4);
    __half* buf0      = (__half*)alloc((size_t)N * D_OUT * 2);
    __half* buf1      = (__half*)alloc((size_t)N * D_OUT * 2);
    (void)ws_size;

    detect_coeffs_kernel<<<1, 64, 0, stream>>>(edges, t, coeffs, flag64);
    hipMemsetAsync(degcnt, 0, (size_t)N * 8, stream);

    int egrid = (int)((E + 255) / 256);
    degree_kernel<<<egrid, 256, 0, stream>>>(edges, E, degcnt, flag64);
    dinv_kernel<<<(N + 255) / 256, 256, 0, stream>>>(degcnt, dinv, N);

    scan_sums_kernel<<<nblocks, 256, 0, stream>>>(degcnt, blocksums, N);
    scan_offsets_kernel<<<1, 1024, 0, stream>>>(blocksums, blockoffs, row_ptr,
                                                nblocks, N);
    scan_write_kernel<<<nblocks, 256, 0, stream>>>(degcnt, blockoffs, row_ptr, N);

    // dst-partitioned scatter: 8 groups x 768 blocks
    scatter_kernel<<<8 * 768, 256, 0, stream>>>(edges, E, row_ptr, fill, csr,
                                                flag64, shift);

    proj_kernel<<<(N + NB - 1) / NB, 256, 0, stream>>>(x, W, b, coeffs, dinv,
                                                       buf0, out, N);

    __half* bufs[2] = {buf0, buf1};
    int hgrid = (int)(((long long)N * 8 + 255) / 256);
    for (int k = 1; k <= K_HOPS; ++k) {
        hop_kernel<<<hgrid, 256, 0, stream>>>(bufs[(k - 1) & 1], bufs[k & 1], out,
                                              csr, row_ptr, dinv, coeffs,
                                              degcnt, k, N);
    }
}